// Round 1
// baseline (8902.419 us; speedup 1.0000x reference)
//
#include <hip/hip_runtime.h>
#include <hip/hip_cooperative_groups.h>

namespace cg = cooperative_groups;

#define Dd 1024
#define Bb 128
#define Tt 256
#define NWG 256
#define NTHR 256

typedef short bf16x8 __attribute__((ext_vector_type(8)));
typedef float f32x4 __attribute__((ext_vector_type(4)));

static __device__ __forceinline__ unsigned short f2bf(float x) {
  unsigned int u = __float_as_uint(x);
  u += 0x7fffu + ((u >> 16) & 1u);   // round-to-nearest-even
  return (unsigned short)(u >> 16);
}
static __device__ __forceinline__ unsigned int pk2(float a, float b) {
  return (unsigned int)f2bf(a) | ((unsigned int)f2bf(b) << 16);
}
static __device__ __forceinline__ bf16x8 as_bf(uint4 u) {
  union { uint4 u; bf16x8 v; } x; x.u = u; return x.v;
}
static __device__ __forceinline__ f32x4 mfma_(bf16x8 a, bf16x8 b, f32x4 c) {
  return __builtin_amdgcn_mfma_f32_16x16x32_bf16(a, b, c, 0, 0, 0);
}
static __device__ __forceinline__ float sigm(float x) { return 1.f / (1.f + __expf(-x)); }
static __device__ __forceinline__ float tanh_s(float x) { return 1.f - 2.f / (__expf(2.f * x) + 1.f); }

// 256 WGs x 256 thr. WG = (batch-half bh, hidden-slice gs of 8 dims).
// LDS: W_ih+W_hh slices (32 gate rows each) packed as MFMA B-fragments:
//   frag index (kc*4 + mmct)*64 + lane, 16B each -> 128 KB.
__global__ void __launch_bounds__(NTHR, 1) lstm_kernel(
    const float* __restrict__ inp, const float* __restrict__ h0,
    const float* __restrict__ c0, const float* __restrict__ W_ih,
    const float* __restrict__ W_hh, const float* __restrict__ b_ih,
    const float* __restrict__ b_hh, const float* __restrict__ fc_w,
    const float* __restrict__ fc_b, float* __restrict__ out,
    unsigned short* __restrict__ hbuf, unsigned short* __restrict__ xbf,
    int use_xbf)
{
  extern __shared__ uint4 ldsW[];   // 8192 fragments = 128 KB
  __shared__ float red[4];

  const int tid = threadIdx.x;
  const int wg  = blockIdx.x;
  const int gid = wg * NTHR + tid;
  cg::grid_group grid = cg::this_grid();

  // ---------- Phase A: inp [B,T,D] f32 -> xbf [T,B,D] bf16 ; h0 -> hbuf[0]
  if (use_xbf) {
    for (int i = gid; i < Tt * Bb * (Dd / 8); i += NWG * NTHR) {
      int d8 = i & 127, b = (i >> 7) & 127, t = i >> 14;
      const float* s = inp + ((size_t)b * Tt + t) * Dd + d8 * 8;
      uint4 p;
      p.x = pk2(s[0], s[1]); p.y = pk2(s[2], s[3]);
      p.z = pk2(s[4], s[5]); p.w = pk2(s[6], s[7]);
      *(uint4*)(xbf + (size_t)i * 8) = p;
    }
  }
  for (int i = gid; i < Bb * Dd / 8; i += NWG * NTHR) {
    const float* s = h0 + (size_t)i * 8;
    uint4 p;
    p.x = pk2(s[0], s[1]); p.y = pk2(s[2], s[3]);
    p.z = pk2(s[4], s[5]); p.w = pk2(s[6], s[7]);
    *(uint4*)(hbuf + (size_t)i * 8) = p;
  }

  // ---------- Phase B: pack W slices into LDS (bf16, fragment order)
  const int gs = wg >> 1;
  const int bh = wg & 1;
  for (int i = tid; i < 8192; i += NTHR) {
    int l = i & 63, mmct = (i >> 6) & 3, kc = i >> 8;
    int cc = l & 15, ct = mmct & 1;
    int row = (((ct << 1) | (cc >> 3)) << 10) | (gs << 3) | (cc & 7);
    int k = kc * 32 + ((l >> 4) << 3);
    const float* s = ((mmct & 2) ? W_hh : W_ih) + (size_t)row * Dd + k;
    uint4 p;
    p.x = pk2(s[0], s[1]); p.y = pk2(s[2], s[3]);
    p.z = pk2(s[4], s[5]); p.w = pk2(s[6], s[7]);
    ldsW[i] = p;
  }

  // ---------- per-thread setup
  const int w = tid >> 6, l = tid & 63;
  const int c = l & 15;
  const int rowbase = bh * 64 + w * 16;
  const int arow = rowbase + c;                 // A-fragment batch row
  const int koff = (l >> 4) << 3;               // k sub-offset within 32-chunk
  const int r0 = ((c >> 3) << 10) | (gs << 3) | (c & 7);        // i/f row
  const int r1 = ((2 + (c >> 3)) << 10) | (gs << 3) | (c & 7);  // g/o row
  const float bias0 = b_ih[r0] + b_hh[r0];
  const float bias1 = b_ih[r1] + b_hh[r1];
  const int dim = (gs << 3) | (c & 7);
  const int crow = rowbase + ((l >> 4) << 2);   // C/D fragment row base
  float creg[4];
  #pragma unroll
  for (int j = 0; j < 4; ++j) creg[j] = c0[(size_t)(crow + j) * Dd + dim];

  float* out_y = out;
  float* out_h = out + Bb;
  float* out_c = out + Bb + (size_t)Bb * Dd;

  const uint4* hA0 = (const uint4*)(hbuf + (size_t)arow * Dd + koff);
  const uint4* hA1 = (const uint4*)(hbuf + (size_t)Bb * Dd + (size_t)arow * Dd + koff);

  grid.sync();

  // ---------- sequential scan
  for (int t = 0; t < Tt; ++t) {
    const int cur = t & 1;
    f32x4 acc0 = {bias0, bias0, bias0, bias0};
    f32x4 acc1 = {bias1, bias1, bias1, bias1};
    const uint4* hA = cur ? hA1 : hA0;

    if (use_xbf) {
      const uint4* xA = (const uint4*)(xbf + ((size_t)t * Bb + arow) * Dd + koff);
      #pragma unroll
      for (int kc = 0; kc < 32; ++kc) {
        uint4 axu = xA[kc * 4];
        uint4 ahu = hA[kc * 4];
        const int lb = kc * 256 + l;
        acc0 = mfma_(as_bf(axu), as_bf(ldsW[lb]),       acc0);
        acc1 = mfma_(as_bf(axu), as_bf(ldsW[lb + 64]),  acc1);
        acc0 = mfma_(as_bf(ahu), as_bf(ldsW[lb + 128]), acc0);
        acc1 = mfma_(as_bf(ahu), as_bf(ldsW[lb + 192]), acc1);
      }
    } else {
      const float* xF = inp + ((size_t)arow * Tt + t) * Dd + koff;
      #pragma unroll 4
      for (int kc = 0; kc < 32; ++kc) {
        const float* xs = xF + kc * 32;
        uint4 axu;
        axu.x = pk2(xs[0], xs[1]); axu.y = pk2(xs[2], xs[3]);
        axu.z = pk2(xs[4], xs[5]); axu.w = pk2(xs[6], xs[7]);
        uint4 ahu = hA[kc * 4];
        const int lb = kc * 256 + l;
        acc0 = mfma_(as_bf(axu), as_bf(ldsW[lb]),       acc0);
        acc1 = mfma_(as_bf(axu), as_bf(ldsW[lb + 64]),  acc1);
        acc0 = mfma_(as_bf(ahu), as_bf(ldsW[lb + 128]), acc0);
        acc1 = mfma_(as_bf(ahu), as_bf(ldsW[lb + 192]), acc1);
      }
    }

    // acc0: cols 0-7 = i, 8-15 = f ; acc1: cols 0-7 = g, 8-15 = o
    float fo0[4], fo1[4];
    #pragma unroll
    for (int j = 0; j < 4; ++j) {
      fo0[j] = __shfl_xor(acc0[j], 8);
      fo1[j] = __shfl_xor(acc1[j], 8);
    }
    if (c < 8) {
      #pragma unroll
      for (int j = 0; j < 4; ++j) {
        float iv = sigm(acc0[j]);
        float fv = sigm(fo0[j]);
        float gv = tanh_s(acc1[j]);
        float ov = sigm(fo1[j]);
        float cn = fv * creg[j] + iv * gv;
        float hn = ov * tanh_s(cn);
        creg[j] = cn;
        size_t off = (size_t)(crow + j) * Dd + dim;
        hbuf[(size_t)(cur ^ 1) * Bb * Dd + off] = f2bf(hn);
        if (t == Tt - 1) {
          out_h[off] = hn;
          out_c[off] = cn;
        }
      }
    }
    grid.sync();
  }

  // ---------- fc head: yhat[b] = sigmoid(hx[b,:] . fc_w + fc_b)
  if (wg < Bb) {
    float s = 0.f;
    for (int k = tid; k < Dd; k += NTHR) s += out_h[(size_t)wg * Dd + k] * fc_w[k];
    #pragma unroll
    for (int off = 32; off > 0; off >>= 1) s += __shfl_down(s, off);
    if (l == 0) red[w] = s;
    __syncthreads();
    if (tid == 0) {
      float tot = red[0] + red[1] + red[2] + red[3] + fc_b[0];
      out_y[wg] = sigm(tot);
    }
  }
}

extern "C" void kernel_launch(void* const* d_in, const int* in_sizes, int n_in,
                              void* d_out, int out_size, void* d_ws, size_t ws_size,
                              hipStream_t stream) {
  (void)in_sizes; (void)n_in; (void)out_size;
  const float* inp  = (const float*)d_in[0];
  const float* h0   = (const float*)d_in[1];
  const float* c0   = (const float*)d_in[2];
  const float* W_ih = (const float*)d_in[3];
  const float* W_hh = (const float*)d_in[4];
  const float* b_ih = (const float*)d_in[5];
  const float* b_hh = (const float*)d_in[6];
  const float* fc_w = (const float*)d_in[7];
  const float* fc_b = (const float*)d_in[8];
  float* out = (float*)d_out;

  size_t hbytes = (size_t)2 * Bb * Dd * 2;          // 512 KB double-buffered h (bf16)
  size_t xbytes = (size_t)Tt * Bb * Dd * 2;         // 64 MB x in bf16 [T,B,D]
  unsigned short* hbuf = (unsigned short*)d_ws;
  unsigned short* xbf  = (unsigned short*)((char*)d_ws + hbytes);
  int use_xbf = (ws_size >= hbytes + xbytes) ? 1 : 0;

  hipFuncSetAttribute((const void*)lstm_kernel,
                      hipFuncAttributeMaxDynamicSharedMemorySize, 131072);

  void* kargs[] = {(void*)&inp, (void*)&h0, (void*)&c0, (void*)&W_ih, (void*)&W_hh,
                   (void*)&b_ih, (void*)&b_hh, (void*)&fc_w, (void*)&fc_b,
                   (void*)&out, (void*)&hbuf, (void*)&xbf, (void*)&use_xbf};
  hipLaunchCooperativeKernel((void*)lstm_kernel, dim3(NWG), dim3(NTHR),
                             kargs, 131072u, stream);
}